// Round 8
// baseline (812.858 us; speedup 1.0000x reference)
//
#include <hip/hip_runtime.h>
#include <hip/hip_cooperative_groups.h>

namespace cg = cooperative_groups;

// GraphSAGE 2-layer. N=50000, E=800000, D_IN=128, D_H=256, D_OUT=128.
//
// R8: R7's fused cooperative build kernel, made robust. R7 failed because the
// coop launch at grid=2048 exceeded the runtime's co-residency limit and was
// silently dropped (no error check). Now: grid sized from the runtime's own
// occupancy query, return code checked, fallback to R6's discrete kernels.
//
// Pipeline (4 launches when coop works):
//   coop build_gather: prep | hist/rank | scan | fill | gather1 (5 grid.sync)
//   gemm<0>: h = relu(A1 @ Wc1.T + b1l)            [N,256] bf16
//   gemm<1>: j_blk0: t = h@W2l.T (bf16) ; j_blk1: out = h@W2r.T + b2l (fp32)
//   gather2: out[n] += mean_{s in adj(n)} t[s]     (node-owned RMW)
//
// Layer-2 trick: mean(h[src])@W2l.T == mean((h@W2l.T)[src]).

typedef __attribute__((ext_vector_type(8))) short bf16x8;
typedef __attribute__((ext_vector_type(4))) float floatx4;

__device__ inline unsigned short f2b(float f) {
  unsigned int x = __float_as_uint(f);
  unsigned int r = (x + 0x7fffu + ((x >> 16) & 1u)) >> 16;
  return (unsigned short)r;
}
__device__ inline float blo(unsigned int u) { return __uint_as_float(u << 16); }
__device__ inline float bhi(unsigned int u) { return __uint_as_float(u & 0xffff0000u); }

#define ACC8(A, u)                                            \
  {                                                           \
    A[0] += blo((u).x); A[1] += bhi((u).x);                   \
    A[2] += blo((u).y); A[3] += bhi((u).y);                   \
    A[4] += blo((u).z); A[5] += bhi((u).z);                   \
    A[6] += blo((u).w); A[7] += bhi((u).w);                   \
  }

// ---------- phase bodies (shared between coop kernel and fallbacks) ----------

__device__ inline void ph_prep(int tid, int nthreads,
                               const float* __restrict__ x,
                               const float* __restrict__ W1l, const float* __restrict__ W1r,
                               const float* __restrict__ W2l, const float* __restrict__ W2r,
                               unsigned short* __restrict__ Wc1, unsigned short* __restrict__ Wc2,
                               unsigned short* __restrict__ A1,
                               int* __restrict__ cnt, int* __restrict__ off, int N, int E) {
  for (int i = tid; i < N * 32; i += nthreads) {
    int n = i >> 5, c = (i & 31) * 4;
    float4 v = *(const float4*)(x + (size_t)n * 128 + c);
    uint2 p;
    p.x = (unsigned int)f2b(v.x) | ((unsigned int)f2b(v.y) << 16);
    p.y = (unsigned int)f2b(v.z) | ((unsigned int)f2b(v.w) << 16);
    *(uint2*)(A1 + (size_t)n * 256 + 128 + c) = p;
  }
  for (int i = tid; i < 65536; i += nthreads) {
    int j = i >> 8, k = i & 255;
    float v1 = (k < 128) ? W1l[j * 128 + k] : W1r[j * 128 + (k - 128)];
    Wc1[i] = f2b(v1);
    float v2 = (j < 128) ? W2l[j * 256 + k] : W2r[(j - 128) * 256 + k];
    Wc2[i] = f2b(v2);
  }
  for (int i = tid; i < N; i += nthreads) cnt[i] = 0;
  if (tid == 0) off[N] = E;
}

__device__ inline void ph_hist(int tid, int nthreads, const int* __restrict__ dst,
                               int* __restrict__ cnt, int* __restrict__ rank, int E) {
  for (int e = tid * 4; e < E; e += nthreads * 4) {
    if (e + 3 < E) {
      int4 d = *(const int4*)(dst + e);
      int4 r;
      r.x = atomicAdd(&cnt[d.x], 1);
      r.y = atomicAdd(&cnt[d.y], 1);
      r.z = atomicAdd(&cnt[d.z], 1);
      r.w = atomicAdd(&cnt[d.w], 1);
      *(int4*)(rank + e) = r;
    } else {
      for (int q = e; q < E; q++) rank[q] = atomicAdd(&cnt[dst[q]], 1);
    }
  }
}

__device__ inline void ph_fill(int tid, int nthreads,
                               const int* __restrict__ src, const int* __restrict__ dst,
                               const int* __restrict__ rank, const int* __restrict__ off,
                               int* __restrict__ csr, int E) {
  for (int e = tid * 4; e < E; e += nthreads * 4) {
    if (e + 3 < E) {
      int4 d = *(const int4*)(dst + e);
      int4 r = *(const int4*)(rank + e);
      int4 s4 = *(const int4*)(src + e);
      csr[off[d.x] + r.x] = s4.x;
      csr[off[d.y] + r.y] = s4.y;
      csr[off[d.z] + r.z] = s4.z;
      csr[off[d.w] + r.w] = s4.w;
    } else {
      for (int q = e; q < E; q++) csr[off[dst[q]] + rank[q]] = src[q];
    }
  }
}

// Gather-mean over adj(wid): 8 slots x 8 lanes, 2 half-row uint4 loads/edge.
__device__ inline void ph_gather1_one(int wid, int lane,
                                      const unsigned short* __restrict__ feat,
                                      const int* __restrict__ csr, const int* __restrict__ off,
                                      unsigned short* __restrict__ A1) {
  const int slot = lane >> 3;
  const int c0 = (lane & 7) * 8;
  const int s0 = off[wid], s1 = off[wid + 1];
  float a[16] = {};
  int e = s0 + slot;
  for (; e + 8 < s1; e += 16) {
    int i0 = csr[e], i1 = csr[e + 8];
    uint4 u0 = *(const uint4*)(feat + (size_t)i0 * 256 + c0);
    uint4 v0 = *(const uint4*)(feat + (size_t)i0 * 256 + 64 + c0);
    uint4 u1 = *(const uint4*)(feat + (size_t)i1 * 256 + c0);
    uint4 v1 = *(const uint4*)(feat + (size_t)i1 * 256 + 64 + c0);
    ACC8(a, u0); ACC8((a + 8), v0);
    ACC8(a, u1); ACC8((a + 8), v1);
  }
  for (; e < s1; e += 8) {
    int i0 = csr[e];
    uint4 u0 = *(const uint4*)(feat + (size_t)i0 * 256 + c0);
    uint4 v0 = *(const uint4*)(feat + (size_t)i0 * 256 + 64 + c0);
    ACC8(a, u0); ACC8((a + 8), v0);
  }
#pragma unroll
  for (int k = 0; k < 16; k++) {
    a[k] += __shfl_xor(a[k], 8, 64);
    a[k] += __shfl_xor(a[k], 16, 64);
    a[k] += __shfl_xor(a[k], 32, 64);
  }
  if (slot == 0) {
    const float inv = 1.0f / fmaxf((float)(s1 - s0), 1.0f);
    uint4 p;
    p.x = (unsigned int)f2b(a[0] * inv) | ((unsigned int)f2b(a[1] * inv) << 16);
    p.y = (unsigned int)f2b(a[2] * inv) | ((unsigned int)f2b(a[3] * inv) << 16);
    p.z = (unsigned int)f2b(a[4] * inv) | ((unsigned int)f2b(a[5] * inv) << 16);
    p.w = (unsigned int)f2b(a[6] * inv) | ((unsigned int)f2b(a[7] * inv) << 16);
    *(uint4*)(A1 + (size_t)wid * 256 + c0) = p;
    p.x = (unsigned int)f2b(a[8] * inv) | ((unsigned int)f2b(a[9] * inv) << 16);
    p.y = (unsigned int)f2b(a[10] * inv) | ((unsigned int)f2b(a[11] * inv) << 16);
    p.z = (unsigned int)f2b(a[12] * inv) | ((unsigned int)f2b(a[13] * inv) << 16);
    p.w = (unsigned int)f2b(a[14] * inv) | ((unsigned int)f2b(a[15] * inv) << 16);
    *(uint4*)(A1 + (size_t)wid * 256 + 64 + c0) = p;
  }
}

// ---------- fused cooperative build+gather1 ----------
__global__ __launch_bounds__(256, 8)
void build_gather_kernel(const float* __restrict__ x,
                         const float* __restrict__ W1l, const float* __restrict__ W1r,
                         const float* __restrict__ W2l, const float* __restrict__ W2r,
                         unsigned short* __restrict__ Wc1, unsigned short* __restrict__ Wc2,
                         unsigned short* __restrict__ A1,
                         int* __restrict__ cnt, int* __restrict__ off,
                         int* __restrict__ bsum, int* __restrict__ rank,
                         int* __restrict__ csr,
                         const int* __restrict__ src, const int* __restrict__ dst,
                         int N, int E, int SB) {
  cg::grid_group grid = cg::this_grid();
  __shared__ int wsum[4];
  __shared__ int bofsS;
  const int tid = blockIdx.x * blockDim.x + threadIdx.x;
  const int nthreads = gridDim.x * blockDim.x;

  ph_prep(tid, nthreads, x, W1l, W1r, W2l, W2r, Wc1, Wc2, A1, cnt, off, N, E);
  grid.sync();
  ph_hist(tid, nthreads, dst, cnt, rank, E);
  grid.sync();

  // per-1024-chunk exclusive scan (256 thr x 4 elems)
  const int b = blockIdx.x;
  if (b < SB) {
    const int base = b * 1024 + threadIdx.x * 4;
    int4 v = make_int4(0, 0, 0, 0);
    if (base + 3 < N) v = *(const int4*)(cnt + base);
    else {
      if (base < N) v.x = cnt[base];
      if (base + 1 < N) v.y = cnt[base + 1];
      if (base + 2 < N) v.z = cnt[base + 2];
    }
    const int tsum = v.x + v.y + v.z + v.w;
    const int lane = threadIdx.x & 63;
    const int wv = threadIdx.x >> 6;
    int s = tsum;
#pragma unroll
    for (int o = 1; o < 64; o <<= 1) {
      int t = __shfl_up(s, o, 64);
      if (lane >= o) s += t;
    }
    if (lane == 63) wsum[wv] = s;
    __syncthreads();
    int wo = 0;
#pragma unroll
    for (int w = 0; w < 4; w++) wo += (w < wv) ? wsum[w] : 0;
    const int excl = wo + s - tsum;
    int4 o4;
    o4.x = excl; o4.y = excl + v.x; o4.z = o4.y + v.y; o4.w = o4.z + v.z;
    if (base + 3 < N) *(int4*)(off + base) = o4;
    else {
      if (base < N) off[base] = o4.x;
      if (base + 1 < N) off[base + 1] = o4.y;
      if (base + 2 < N) off[base + 2] = o4.z;
    }
    if (threadIdx.x == 255) bsum[b] = wo + s;
  }
  grid.sync();

  // add chunk-prefix to off
  if (b > 0 && b < SB) {
    if (threadIdx.x < 64) {
      int v = (threadIdx.x < b) ? bsum[threadIdx.x] : 0;
#pragma unroll
      for (int o = 1; o < 64; o <<= 1) v += __shfl_xor(v, o, 64);
      if (threadIdx.x == 0) bofsS = v;
    }
    __syncthreads();
    const int bofs = bofsS;
    const int base = b * 1024 + threadIdx.x * 4;
    if (base + 3 < N) {
      int4 o4 = *(const int4*)(off + base);
      o4.x += bofs; o4.y += bofs; o4.z += bofs; o4.w += bofs;
      *(int4*)(off + base) = o4;
    } else {
      if (base < N) off[base] += bofs;
      if (base + 1 < N) off[base + 1] += bofs;
      if (base + 2 < N) off[base + 2] += bofs;
    }
  }
  grid.sync();

  ph_fill(tid, nthreads, src, dst, rank, off, csr, E);
  grid.sync();

  const int nwaves = nthreads >> 6;
  const int lane = threadIdx.x & 63;
  const unsigned short* feat = A1 + 128;
  for (int wid = tid >> 6; wid < N; wid += nwaves)
    ph_gather1_one(wid, lane, feat, csr, off, A1);
}

// ---------- discrete fallback kernels (R6 structure) ----------

__global__ void prep_kernel(const float* __restrict__ x,
                            const float* __restrict__ W1l, const float* __restrict__ W1r,
                            const float* __restrict__ W2l, const float* __restrict__ W2r,
                            unsigned short* __restrict__ Wc1, unsigned short* __restrict__ Wc2,
                            unsigned short* __restrict__ A1,
                            int* __restrict__ cnt, int* __restrict__ off, int N, int E) {
  int tid = blockIdx.x * blockDim.x + threadIdx.x;
  ph_prep(tid, gridDim.x * blockDim.x, x, W1l, W1r, W2l, W2r, Wc1, Wc2, A1, cnt, off, N, E);
}

__global__ void hist_kernel(const int* __restrict__ dst, int* __restrict__ cnt,
                            int* __restrict__ rank, int E) {
  int tid = blockIdx.x * blockDim.x + threadIdx.x;
  ph_hist(tid, gridDim.x * blockDim.x, dst, cnt, rank, E);
}

__global__ __launch_bounds__(1024) void scan_blocks_kernel(const int* __restrict__ cnt,
                                                           int* __restrict__ off,
                                                           int* __restrict__ bsum, int N) {
  __shared__ int wsum[16];
  __shared__ int wincl[16];
  const int tid = threadIdx.x;
  const int lane = tid & 63;
  const int wv = tid >> 6;
  const int i = blockIdx.x * 1024 + tid;
  const int v = (i < N) ? cnt[i] : 0;
  int s = v;
#pragma unroll
  for (int o = 1; o < 64; o <<= 1) {
    int t = __shfl_up(s, o, 64);
    if (lane >= o) s += t;
  }
  if (lane == 63) wsum[wv] = s;
  __syncthreads();
  if (tid < 16) {
    int ws = wsum[tid];
#pragma unroll
    for (int o = 1; o < 16; o <<= 1) {
      int t = __shfl_up(ws, o, 16);
      if ((tid & 15) >= o) ws += t;
    }
    wincl[tid] = ws;
  }
  __syncthreads();
  const int wo = wv ? wincl[wv - 1] : 0;
  if (i < N) off[i] = wo + s - v;
  if (tid == 1023) bsum[blockIdx.x] = wo + s;
}

__global__ __launch_bounds__(1024) void scan_add_kernel(int* __restrict__ off,
                                                        const int* __restrict__ bsum, int N, int SB) {
  __shared__ int bofs[64];
  const int tid = threadIdx.x;
  if (tid < 64) {
    int v = (tid < SB) ? bsum[tid] : 0;
    int s = v;
#pragma unroll
    for (int o = 1; o < 64; o <<= 1) {
      int t = __shfl_up(s, o, 64);
      if (tid >= o) s += t;
    }
    bofs[tid] = s - v;
  }
  __syncthreads();
  int i = blockIdx.x * 1024 + tid;
  if (i < N) off[i] = off[i] + bofs[blockIdx.x];
}

__global__ void fill_kernel(const int* __restrict__ src, const int* __restrict__ dst,
                            const int* __restrict__ rank, const int* __restrict__ off,
                            int* __restrict__ csr, int E) {
  int tid = blockIdx.x * blockDim.x + threadIdx.x;
  ph_fill(tid, gridDim.x * blockDim.x, src, dst, rank, off, csr, E);
}

__global__ void gather1_kernel(const unsigned short* __restrict__ feat,
                               const int* __restrict__ csr, const int* __restrict__ off,
                               unsigned short* __restrict__ A1, int N) {
  int wid = (blockIdx.x * blockDim.x + threadIdx.x) >> 6;
  if (wid >= N) return;
  ph_gather1_one(wid, threadIdx.x & 63, feat, csr, off, A1);
}

// Gather-mean of t (stride 128 ushorts); accumulate into fp32 out.
__global__ void gather2_kernel(const unsigned short* __restrict__ t,
                               const int* __restrict__ csr, const int* __restrict__ off,
                               float* __restrict__ out, int N) {
  int wid = (blockIdx.x * blockDim.x + threadIdx.x) >> 6;
  if (wid >= N) return;
  const int lane = threadIdx.x & 63;
  const int slot = lane >> 3;
  const int c0 = (lane & 7) * 8;
  const int s0 = off[wid], s1 = off[wid + 1];
  float a[16] = {};
  int e = s0 + slot;
  for (; e + 8 < s1; e += 16) {
    int i0 = csr[e], i1 = csr[e + 8];
    uint4 u0 = *(const uint4*)(t + (size_t)i0 * 128 + c0);
    uint4 v0 = *(const uint4*)(t + (size_t)i0 * 128 + 64 + c0);
    uint4 u1 = *(const uint4*)(t + (size_t)i1 * 128 + c0);
    uint4 v1 = *(const uint4*)(t + (size_t)i1 * 128 + 64 + c0);
    ACC8(a, u0); ACC8((a + 8), v0);
    ACC8(a, u1); ACC8((a + 8), v1);
  }
  for (; e < s1; e += 8) {
    int i0 = csr[e];
    uint4 u0 = *(const uint4*)(t + (size_t)i0 * 128 + c0);
    uint4 v0 = *(const uint4*)(t + (size_t)i0 * 128 + 64 + c0);
    ACC8(a, u0); ACC8((a + 8), v0);
  }
#pragma unroll
  for (int k = 0; k < 16; k++) {
    a[k] += __shfl_xor(a[k], 8, 64);
    a[k] += __shfl_xor(a[k], 16, 64);
    a[k] += __shfl_xor(a[k], 32, 64);
  }
  if (slot == 0) {
    const float inv = 1.0f / fmaxf((float)(s1 - s0), 1.0f);
    float4* o0 = (float4*)(out + (size_t)wid * 128 + c0);
    float4* o1 = (float4*)(out + (size_t)wid * 128 + 64 + c0);
    float4 r0 = o0[0], r1 = o0[1], r2 = o1[0], r3 = o1[1];
    r0.x += a[0] * inv;  r0.y += a[1] * inv;  r0.z += a[2] * inv;  r0.w += a[3] * inv;
    r1.x += a[4] * inv;  r1.y += a[5] * inv;  r1.z += a[6] * inv;  r1.w += a[7] * inv;
    r2.x += a[8] * inv;  r2.y += a[9] * inv;  r2.z += a[10] * inv; r2.w += a[11] * inv;
    r3.x += a[12] * inv; r3.y += a[13] * inv; r3.z += a[14] * inv; r3.w += a[15] * inv;
    o0[0] = r0; o0[1] = r1; o1[0] = r2; o1[1] = r3;
  }
}

// bf16 MFMA GEMM (unchanged from R6).
template <int MODE>
__global__ __launch_bounds__(256, 2)
void gemm_bf16(const unsigned short* __restrict__ A, const unsigned short* __restrict__ W,
               const float* __restrict__ bias, unsigned short* __restrict__ Hout,
               float* __restrict__ Fout, int M) {
  constexpr int LDA = 72;
  __shared__ __align__(16) unsigned short As[128 * LDA];
  __shared__ __align__(16) unsigned short Ws[128 * LDA];
  const int t = threadIdx.x;
  const int lane = t & 63;
  const int wave = t >> 6;
  const int wm = (wave & 1) * 64;
  const int wn = (wave >> 1) * 64;
  const int l15 = lane & 15;
  const int quad = lane >> 4;
  const int m_blk = blockIdx.x * 128;
  const int j_blk = blockIdx.y * 128;

  floatx4 acc[4][4] = {};

  for (int kc = 0; kc < 256; kc += 64) {
    __syncthreads();
#pragma unroll
    for (int i = 0; i < 4; i++) {
      int c = t + 256 * i;
      int row = c >> 3;
      int col = (c & 7) * 8;
      int ar = m_blk + row;
      if (ar >= M) ar = M - 1;
      uint4 av = *(const uint4*)(A + (size_t)ar * 256 + kc + col);
      *(uint4*)(As + row * LDA + col) = av;
      uint4 wv = *(const uint4*)(W + (size_t)(j_blk + row) * 256 + kc + col);
      *(uint4*)(Ws + row * LDA + col) = wv;
    }
    __syncthreads();
#pragma unroll
    for (int ks = 0; ks < 64; ks += 32) {
      bf16x8 af[4], bfr[4];
#pragma unroll
      for (int mt = 0; mt < 4; mt++)
        af[mt] = *(const bf16x8*)(As + (wm + mt * 16 + l15) * LDA + ks + quad * 8);
#pragma unroll
      for (int nt = 0; nt < 4; nt++)
        bfr[nt] = *(const bf16x8*)(Ws + (wn + nt * 16 + l15) * LDA + ks + quad * 8);
#pragma unroll
      for (int mt = 0; mt < 4; mt++)
#pragma unroll
        for (int nt = 0; nt < 4; nt++)
          acc[mt][nt] = __builtin_amdgcn_mfma_f32_16x16x32_bf16(af[mt], bfr[nt], acc[mt][nt], 0, 0, 0);
    }
  }

#pragma unroll
  for (int mt = 0; mt < 4; mt++) {
#pragma unroll
    for (int nt = 0; nt < 4; nt++) {
      const int jl = wn + nt * 16 + l15;
      float bv = 0.f;
      if (MODE == 0) bv = bias[j_blk + jl];
      else if (j_blk != 0) bv = bias[jl];
#pragma unroll
      for (int r = 0; r < 4; r++) {
        const int node = m_blk + wm + mt * 16 + quad * 4 + r;
        if (node >= M) continue;
        const float v = acc[mt][nt][r];
        if (MODE == 0) {
          Hout[(size_t)node * 256 + j_blk + jl] = f2b(fmaxf(v + bv, 0.f));
        } else if (j_blk == 0) {
          Hout[(size_t)node * 128 + jl] = f2b(v);
        } else {
          Fout[(size_t)node * 128 + jl] = v + bv;
        }
      }
    }
  }
}

extern "C" void kernel_launch(void* const* d_in, const int* in_sizes, int n_in,
                              void* d_out, int out_size, void* d_ws, size_t ws_size,
                              hipStream_t stream) {
  const float* x   = (const float*)d_in[0];
  const int*  eidx = (const int*)d_in[1];
  const float* W1l = (const float*)d_in[2];
  const float* b1l = (const float*)d_in[3];
  const float* W1r = (const float*)d_in[4];
  const float* W2l = (const float*)d_in[5];
  const float* b2l = (const float*)d_in[6];
  const float* W2r = (const float*)d_in[7];
  float* out = (float*)d_out;

  int N = in_sizes[0] / 128;
  int E = in_sizes[1] / 2;
  const int* src = eidx;
  const int* dst = eidx + E;

  int* cnt  = (int*)d_ws;          // [N]
  int* off  = cnt + N;             // [N+1]
  int* bsum = off + N + 1;         // [64]
  int* rank = bsum + 64;           // [E]
  int* csr  = rank + E;            // [E]
  size_t ioff = ((size_t)(N + N + 1 + 64 + 2 * E) * 4 + 15) & ~(size_t)15;
  unsigned short* A1  = (unsigned short*)((char*)d_ws + ioff);  // [N][256]
  unsigned short* h   = A1 + (size_t)N * 256;                   // [N][256]
  unsigned short* tb  = h + (size_t)N * 256;                    // [N][128]
  unsigned short* Wc1 = tb + (size_t)N * 128;                   // [256][256]
  unsigned short* Wc2 = Wc1 + 65536;                            // [256][256]

  int SB = (N + 1023) / 1024;  // 49

  // Size coop grid from the runtime's occupancy (host-side queries: capture-safe).
  int dev = 0;
  (void)hipGetDevice(&dev);
  int numCU = 0;
  (void)hipDeviceGetAttribute(&numCU, hipDeviceAttributeMultiprocessorCount, dev);
  int maxBlk = 0;
  (void)hipOccupancyMaxActiveBlocksPerMultiprocessor(
      &maxBlk, (const void*)build_gather_kernel, 256, 0);
  long gridB = (long)maxBlk * (numCU > 0 ? numCU : 0);
  if (gridB > 2048) gridB = 2048;

  bool coop_ok = false;
  if (gridB >= SB + 1) {
    void* cargs[] = {(void*)&x, (void*)&W1l, (void*)&W1r, (void*)&W2l, (void*)&W2r,
                     (void*)&Wc1, (void*)&Wc2, (void*)&A1,
                     (void*)&cnt, (void*)&off, (void*)&bsum, (void*)&rank, (void*)&csr,
                     (void*)&src, (void*)&dst, (void*)&N, (void*)&E, (void*)&SB};
    hipError_t err = hipLaunchCooperativeKernel((const void*)build_gather_kernel,
                                                dim3((unsigned)gridB), dim3(256),
                                                cargs, 0, stream);
    coop_ok = (err == hipSuccess);
  }

  if (!coop_ok) {
    // Discrete fallback (R6 structure).
    prep_kernel<<<(N * 32 + 255) / 256, 256, 0, stream>>>(x, W1l, W1r, W2l, W2r,
                                                          Wc1, Wc2, A1, cnt, off, N, E);
    hist_kernel<<<(E / 4 + 255) / 256, 256, 0, stream>>>(dst, cnt, rank, E);
    scan_blocks_kernel<<<SB, 1024, 0, stream>>>(cnt, off, bsum, N);
    scan_add_kernel<<<SB, 1024, 0, stream>>>(off, bsum, N, SB);
    fill_kernel<<<(E / 4 + 255) / 256, 256, 0, stream>>>(src, dst, rank, off, csr, E);
    gather1_kernel<<<(N + 3) / 4, 256, 0, stream>>>(A1 + 128, csr, off, A1, N);
  }

  dim3 gg((N + 127) / 128, 2);
  gemm_bf16<0><<<gg, 256, 0, stream>>>(A1, Wc1, b1l, h, nullptr, N);
  gemm_bf16<1><<<gg, 256, 0, stream>>>(h, Wc2, b2l, tb, out, N);

  const int gblocks = (N + 3) / 4;  // 1 wave per node
  gather2_kernel<<<gblocks, 256, 0, stream>>>(tb, csr, off, out, N);
}

// Round 9
// 387.726 us; speedup vs baseline: 2.0965x; 2.0965x over previous
//
#include <hip/hip_runtime.h>

// GraphSAGE 2-layer. N=50000, E=800000, D_IN=128, D_H=256, D_OUT=128.
//
// R9: fused build kernel with HAND-ROLLED global barrier. R8 proved the fused
// phase code correct but ROCm's cg::grid.sync() cost ~200us/sync (1060us
// total, all pipes idle). Replacement: 256 blocks x 256 threads (<= 1
// block/CU -> co-residency guaranteed), arrive-and-spin barrier on
// device-scope atomics (counters zeroed by a 64B hipMemsetAsync before the
// kernel). 6 launches total.
//
// Pipeline:
//   memset bar[16] = 0
//   build_fused: prep | bar | hist/rank | bar | scanA | bar | scanB | bar | fill
//   gather1: A1 cols 0..127 = mean_{s in adj(n)} bf16(x[s])
//   gemm<0>: h = relu(A1 @ Wc1.T + b1l)            [N,256] bf16
//   gemm<1>: j_blk0: t = h@W2l.T (bf16) ; j_blk1: out = h@W2r.T + b2l (fp32)
//   gather2: out[n] += mean_{s in adj(n)} t[s]     (node-owned RMW)
//
// Layer-2 trick: mean(h[src])@W2l.T == mean((h@W2l.T)[src]).

typedef __attribute__((ext_vector_type(8))) short bf16x8;
typedef __attribute__((ext_vector_type(4))) float floatx4;

__device__ inline unsigned short f2b(float f) {
  unsigned int x = __float_as_uint(f);
  unsigned int r = (x + 0x7fffu + ((x >> 16) & 1u)) >> 16;
  return (unsigned short)r;
}
__device__ inline float blo(unsigned int u) { return __uint_as_float(u << 16); }
__device__ inline float bhi(unsigned int u) { return __uint_as_float(u & 0xffff0000u); }

#define ACC8(A, u)                                            \
  {                                                           \
    A[0] += blo((u).x); A[1] += bhi((u).x);                   \
    A[2] += blo((u).y); A[3] += bhi((u).y);                   \
    A[4] += blo((u).z); A[5] += bhi((u).z);                   \
    A[6] += blo((u).w); A[7] += bhi((u).w);                   \
  }

// Arrive-and-spin global barrier. Safe: grid = 256 blocks of 256 threads
// (1 block/CU capacity) -> all blocks co-resident. Bounded spin is anti-hang
// insurance only.
__device__ __forceinline__ void gbar(int* bar, int idx, int nblk) {
  __syncthreads();
  if (threadIdx.x == 0) {
    __threadfence();  // release prior global writes
    __hip_atomic_fetch_add(&bar[idx], 1, __ATOMIC_RELEASE, __HIP_MEMORY_SCOPE_AGENT);
    long spins = 0;
    while (__hip_atomic_load(&bar[idx], __ATOMIC_ACQUIRE, __HIP_MEMORY_SCOPE_AGENT) < nblk) {
      __builtin_amdgcn_s_sleep(1);
      if (++spins > (1L << 31)) break;
    }
    __threadfence();  // acquire
  }
  __syncthreads();
}

// ---------- phase bodies (verified in R8) ----------

__device__ inline void ph_prep(int tid, int nthreads,
                               const float* __restrict__ x,
                               const float* __restrict__ W1l, const float* __restrict__ W1r,
                               const float* __restrict__ W2l, const float* __restrict__ W2r,
                               unsigned short* __restrict__ Wc1, unsigned short* __restrict__ Wc2,
                               unsigned short* __restrict__ A1,
                               int* __restrict__ cnt, int* __restrict__ off, int N, int E) {
  for (int i = tid; i < N * 32; i += nthreads) {
    int n = i >> 5, c = (i & 31) * 4;
    float4 v = *(const float4*)(x + (size_t)n * 128 + c);
    uint2 p;
    p.x = (unsigned int)f2b(v.x) | ((unsigned int)f2b(v.y) << 16);
    p.y = (unsigned int)f2b(v.z) | ((unsigned int)f2b(v.w) << 16);
    *(uint2*)(A1 + (size_t)n * 256 + 128 + c) = p;
  }
  for (int i = tid; i < 65536; i += nthreads) {
    int j = i >> 8, k = i & 255;
    float v1 = (k < 128) ? W1l[j * 128 + k] : W1r[j * 128 + (k - 128)];
    Wc1[i] = f2b(v1);
    float v2 = (j < 128) ? W2l[j * 256 + k] : W2r[(j - 128) * 256 + k];
    Wc2[i] = f2b(v2);
  }
  for (int i = tid; i < N; i += nthreads) cnt[i] = 0;
  if (tid == 0) off[N] = E;
}

__device__ inline void ph_hist(int tid, int nthreads, const int* __restrict__ dst,
                               int* __restrict__ cnt, int* __restrict__ rank, int E) {
  for (int e = tid * 4; e < E; e += nthreads * 4) {
    if (e + 3 < E) {
      int4 d = *(const int4*)(dst + e);
      int4 r;
      r.x = atomicAdd(&cnt[d.x], 1);
      r.y = atomicAdd(&cnt[d.y], 1);
      r.z = atomicAdd(&cnt[d.z], 1);
      r.w = atomicAdd(&cnt[d.w], 1);
      *(int4*)(rank + e) = r;
    } else {
      for (int q = e; q < E; q++) rank[q] = atomicAdd(&cnt[dst[q]], 1);
    }
  }
}

__device__ inline void ph_fill(int tid, int nthreads,
                               const int* __restrict__ src, const int* __restrict__ dst,
                               const int* __restrict__ rank, const int* __restrict__ off,
                               int* __restrict__ csr, int E) {
  for (int e = tid * 4; e < E; e += nthreads * 4) {
    if (e + 3 < E) {
      int4 d = *(const int4*)(dst + e);
      int4 r = *(const int4*)(rank + e);
      int4 s4 = *(const int4*)(src + e);
      csr[off[d.x] + r.x] = s4.x;
      csr[off[d.y] + r.y] = s4.y;
      csr[off[d.z] + r.z] = s4.z;
      csr[off[d.w] + r.w] = s4.w;
    } else {
      for (int q = e; q < E; q++) csr[off[dst[q]] + rank[q]] = src[q];
    }
  }
}

// ---------- fused build: prep | hist | scan | fill ----------
__global__ __launch_bounds__(256)
void build_fused_kernel(const float* __restrict__ x,
                        const float* __restrict__ W1l, const float* __restrict__ W1r,
                        const float* __restrict__ W2l, const float* __restrict__ W2r,
                        unsigned short* __restrict__ Wc1, unsigned short* __restrict__ Wc2,
                        unsigned short* __restrict__ A1,
                        int* __restrict__ cnt, int* __restrict__ off,
                        int* __restrict__ bsum, int* __restrict__ bar,
                        int* __restrict__ rank, int* __restrict__ csr,
                        const int* __restrict__ src, const int* __restrict__ dst,
                        int N, int E, int SB) {
  __shared__ int wsum[4];
  __shared__ int bofsS;
  const int tid = blockIdx.x * blockDim.x + threadIdx.x;
  const int nthreads = gridDim.x * blockDim.x;
  const int nblk = gridDim.x;

  ph_prep(tid, nthreads, x, W1l, W1r, W2l, W2r, Wc1, Wc2, A1, cnt, off, N, E);
  gbar(bar, 0, nblk);

  ph_hist(tid, nthreads, dst, cnt, rank, E);
  gbar(bar, 1, nblk);

  // scanA: per-1024-chunk exclusive scan (256 thr x 4 elems), totals -> bsum
  const int b = blockIdx.x;
  if (b < SB) {
    const int base = b * 1024 + threadIdx.x * 4;
    int4 v = make_int4(0, 0, 0, 0);
    if (base + 3 < N) v = *(const int4*)(cnt + base);
    else {
      if (base < N) v.x = cnt[base];
      if (base + 1 < N) v.y = cnt[base + 1];
      if (base + 2 < N) v.z = cnt[base + 2];
    }
    const int tsum = v.x + v.y + v.z + v.w;
    const int lane = threadIdx.x & 63;
    const int wv = threadIdx.x >> 6;
    int s = tsum;
#pragma unroll
    for (int o = 1; o < 64; o <<= 1) {
      int t = __shfl_up(s, o, 64);
      if (lane >= o) s += t;
    }
    if (lane == 63) wsum[wv] = s;
    __syncthreads();
    int wo = 0;
#pragma unroll
    for (int w = 0; w < 4; w++) wo += (w < wv) ? wsum[w] : 0;
    const int excl = wo + s - tsum;
    int4 o4;
    o4.x = excl; o4.y = excl + v.x; o4.z = o4.y + v.y; o4.w = o4.z + v.z;
    if (base + 3 < N) *(int4*)(off + base) = o4;
    else {
      if (base < N) off[base] = o4.x;
      if (base + 1 < N) off[base + 1] = o4.y;
      if (base + 2 < N) off[base + 2] = o4.z;
    }
    if (threadIdx.x == 255) bsum[b] = wo + s;
  }
  gbar(bar, 2, nblk);

  // scanB: each chunk-block adds prefix of bsum[0..b)
  if (b > 0 && b < SB) {
    if (threadIdx.x < 64) {
      int v = (threadIdx.x < b) ? bsum[threadIdx.x] : 0;
#pragma unroll
      for (int o = 1; o < 64; o <<= 1) v += __shfl_xor(v, o, 64);
      if (threadIdx.x == 0) bofsS = v;
    }
    __syncthreads();
    const int bofs = bofsS;
    const int base = b * 1024 + threadIdx.x * 4;
    if (base + 3 < N) {
      int4 o4 = *(const int4*)(off + base);
      o4.x += bofs; o4.y += bofs; o4.z += bofs; o4.w += bofs;
      *(int4*)(off + base) = o4;
    } else {
      if (base < N) off[base] += bofs;
      if (base + 1 < N) off[base + 1] += bofs;
      if (base + 2 < N) off[base + 2] += bofs;
    }
  }
  gbar(bar, 3, nblk);

  ph_fill(tid, nthreads, src, dst, rank, off, csr, E);
}

// Gather-mean over adj(wid): 8 slots x 8 lanes, 2 half-row uint4 loads/edge.
__device__ inline void ph_gather1_one(int wid, int lane,
                                      const unsigned short* __restrict__ feat,
                                      const int* __restrict__ csr, const int* __restrict__ off,
                                      unsigned short* __restrict__ A1) {
  const int slot = lane >> 3;
  const int c0 = (lane & 7) * 8;
  const int s0 = off[wid], s1 = off[wid + 1];
  float a[16] = {};
  int e = s0 + slot;
  for (; e + 8 < s1; e += 16) {
    int i0 = csr[e], i1 = csr[e + 8];
    uint4 u0 = *(const uint4*)(feat + (size_t)i0 * 256 + c0);
    uint4 v0 = *(const uint4*)(feat + (size_t)i0 * 256 + 64 + c0);
    uint4 u1 = *(const uint4*)(feat + (size_t)i1 * 256 + c0);
    uint4 v1 = *(const uint4*)(feat + (size_t)i1 * 256 + 64 + c0);
    ACC8(a, u0); ACC8((a + 8), v0);
    ACC8(a, u1); ACC8((a + 8), v1);
  }
  for (; e < s1; e += 8) {
    int i0 = csr[e];
    uint4 u0 = *(const uint4*)(feat + (size_t)i0 * 256 + c0);
    uint4 v0 = *(const uint4*)(feat + (size_t)i0 * 256 + 64 + c0);
    ACC8(a, u0); ACC8((a + 8), v0);
  }
#pragma unroll
  for (int k = 0; k < 16; k++) {
    a[k] += __shfl_xor(a[k], 8, 64);
    a[k] += __shfl_xor(a[k], 16, 64);
    a[k] += __shfl_xor(a[k], 32, 64);
  }
  if (slot == 0) {
    const float inv = 1.0f / fmaxf((float)(s1 - s0), 1.0f);
    uint4 p;
    p.x = (unsigned int)f2b(a[0] * inv) | ((unsigned int)f2b(a[1] * inv) << 16);
    p.y = (unsigned int)f2b(a[2] * inv) | ((unsigned int)f2b(a[3] * inv) << 16);
    p.z = (unsigned int)f2b(a[4] * inv) | ((unsigned int)f2b(a[5] * inv) << 16);
    p.w = (unsigned int)f2b(a[6] * inv) | ((unsigned int)f2b(a[7] * inv) << 16);
    *(uint4*)(A1 + (size_t)wid * 256 + c0) = p;
    p.x = (unsigned int)f2b(a[8] * inv) | ((unsigned int)f2b(a[9] * inv) << 16);
    p.y = (unsigned int)f2b(a[10] * inv) | ((unsigned int)f2b(a[11] * inv) << 16);
    p.z = (unsigned int)f2b(a[12] * inv) | ((unsigned int)f2b(a[13] * inv) << 16);
    p.w = (unsigned int)f2b(a[14] * inv) | ((unsigned int)f2b(a[15] * inv) << 16);
    *(uint4*)(A1 + (size_t)wid * 256 + 64 + c0) = p;
  }
}

__global__ void gather1_kernel(const unsigned short* __restrict__ feat,
                               const int* __restrict__ csr, const int* __restrict__ off,
                               unsigned short* __restrict__ A1, int N) {
  int wid = (blockIdx.x * blockDim.x + threadIdx.x) >> 6;
  if (wid >= N) return;
  ph_gather1_one(wid, threadIdx.x & 63, feat, csr, off, A1);
}

// Gather-mean of t (stride 128 ushorts); accumulate into fp32 out.
__global__ void gather2_kernel(const unsigned short* __restrict__ t,
                               const int* __restrict__ csr, const int* __restrict__ off,
                               float* __restrict__ out, int N) {
  int wid = (blockIdx.x * blockDim.x + threadIdx.x) >> 6;
  if (wid >= N) return;
  const int lane = threadIdx.x & 63;
  const int slot = lane >> 3;
  const int c0 = (lane & 7) * 8;
  const int s0 = off[wid], s1 = off[wid + 1];
  float a[16] = {};
  int e = s0 + slot;
  for (; e + 8 < s1; e += 16) {
    int i0 = csr[e], i1 = csr[e + 8];
    uint4 u0 = *(const uint4*)(t + (size_t)i0 * 128 + c0);
    uint4 v0 = *(const uint4*)(t + (size_t)i0 * 128 + 64 + c0);
    uint4 u1 = *(const uint4*)(t + (size_t)i1 * 128 + c0);
    uint4 v1 = *(const uint4*)(t + (size_t)i1 * 128 + 64 + c0);
    ACC8(a, u0); ACC8((a + 8), v0);
    ACC8(a, u1); ACC8((a + 8), v1);
  }
  for (; e < s1; e += 8) {
    int i0 = csr[e];
    uint4 u0 = *(const uint4*)(t + (size_t)i0 * 128 + c0);
    uint4 v0 = *(const uint4*)(t + (size_t)i0 * 128 + 64 + c0);
    ACC8(a, u0); ACC8((a + 8), v0);
  }
#pragma unroll
  for (int k = 0; k < 16; k++) {
    a[k] += __shfl_xor(a[k], 8, 64);
    a[k] += __shfl_xor(a[k], 16, 64);
    a[k] += __shfl_xor(a[k], 32, 64);
  }
  if (slot == 0) {
    const float inv = 1.0f / fmaxf((float)(s1 - s0), 1.0f);
    float4* o0 = (float4*)(out + (size_t)wid * 128 + c0);
    float4* o1 = (float4*)(out + (size_t)wid * 128 + 64 + c0);
    float4 r0 = o0[0], r1 = o0[1], r2 = o1[0], r3 = o1[1];
    r0.x += a[0] * inv;  r0.y += a[1] * inv;  r0.z += a[2] * inv;  r0.w += a[3] * inv;
    r1.x += a[4] * inv;  r1.y += a[5] * inv;  r1.z += a[6] * inv;  r1.w += a[7] * inv;
    r2.x += a[8] * inv;  r2.y += a[9] * inv;  r2.z += a[10] * inv; r2.w += a[11] * inv;
    r3.x += a[12] * inv; r3.y += a[13] * inv; r3.z += a[14] * inv; r3.w += a[15] * inv;
    o0[0] = r0; o0[1] = r1; o1[0] = r2; o1[1] = r3;
  }
}

// bf16 MFMA GEMM (unchanged from R6).
template <int MODE>
__global__ __launch_bounds__(256, 2)
void gemm_bf16(const unsigned short* __restrict__ A, const unsigned short* __restrict__ W,
               const float* __restrict__ bias, unsigned short* __restrict__ Hout,
               float* __restrict__ Fout, int M) {
  constexpr int LDA = 72;
  __shared__ __align__(16) unsigned short As[128 * LDA];
  __shared__ __align__(16) unsigned short Ws[128 * LDA];
  const int t = threadIdx.x;
  const int lane = t & 63;
  const int wave = t >> 6;
  const int wm = (wave & 1) * 64;
  const int wn = (wave >> 1) * 64;
  const int l15 = lane & 15;
  const int quad = lane >> 4;
  const int m_blk = blockIdx.x * 128;
  const int j_blk = blockIdx.y * 128;

  floatx4 acc[4][4] = {};

  for (int kc = 0; kc < 256; kc += 64) {
    __syncthreads();
#pragma unroll
    for (int i = 0; i < 4; i++) {
      int c = t + 256 * i;
      int row = c >> 3;
      int col = (c & 7) * 8;
      int ar = m_blk + row;
      if (ar >= M) ar = M - 1;
      uint4 av = *(const uint4*)(A + (size_t)ar * 256 + kc + col);
      *(uint4*)(As + row * LDA + col) = av;
      uint4 wv = *(const uint4*)(W + (size_t)(j_blk + row) * 256 + kc + col);
      *(uint4*)(Ws + row * LDA + col) = wv;
    }
    __syncthreads();
#pragma unroll
    for (int ks = 0; ks < 64; ks += 32) {
      bf16x8 af[4], bfr[4];
#pragma unroll
      for (int mt = 0; mt < 4; mt++)
        af[mt] = *(const bf16x8*)(As + (wm + mt * 16 + l15) * LDA + ks + quad * 8);
#pragma unroll
      for (int nt = 0; nt < 4; nt++)
        bfr[nt] = *(const bf16x8*)(Ws + (wn + nt * 16 + l15) * LDA + ks + quad * 8);
#pragma unroll
      for (int mt = 0; mt < 4; mt++)
#pragma unroll
        for (int nt = 0; nt < 4; nt++)
          acc[mt][nt] = __builtin_amdgcn_mfma_f32_16x16x32_bf16(af[mt], bfr[nt], acc[mt][nt], 0, 0, 0);
    }
  }

#pragma unroll
  for (int mt = 0; mt < 4; mt++) {
#pragma unroll
    for (int nt = 0; nt < 4; nt++) {
      const int jl = wn + nt * 16 + l15;
      float bv = 0.f;
      if (MODE == 0) bv = bias[j_blk + jl];
      else if (j_blk != 0) bv = bias[jl];
#pragma unroll
      for (int r = 0; r < 4; r++) {
        const int node = m_blk + wm + mt * 16 + quad * 4 + r;
        if (node >= M) continue;
        const float v = acc[mt][nt][r];
        if (MODE == 0) {
          Hout[(size_t)node * 256 + j_blk + jl] = f2b(fmaxf(v + bv, 0.f));
        } else if (j_blk == 0) {
          Hout[(size_t)node * 128 + jl] = f2b(v);
        } else {
          Fout[(size_t)node * 128 + jl] = v + bv;
        }
      }
    }
  }
}

extern "C" void kernel_launch(void* const* d_in, const int* in_sizes, int n_in,
                              void* d_out, int out_size, void* d_ws, size_t ws_size,
                              hipStream_t stream) {
  const float* x   = (const float*)d_in[0];
  const int*  eidx = (const int*)d_in[1];
  const float* W1l = (const float*)d_in[2];
  const float* b1l = (const float*)d_in[3];
  const float* W1r = (const float*)d_in[4];
  const float* W2l = (const float*)d_in[5];
  const float* b2l = (const float*)d_in[6];
  const float* W2r = (const float*)d_in[7];
  float* out = (float*)d_out;

  int N = in_sizes[0] / 128;
  int E = in_sizes[1] / 2;
  const int* src = eidx;
  const int* dst = eidx + E;

  int* cnt  = (int*)d_ws;          // [N]
  int* off  = cnt + N;             // [N+1]
  int* bsum = off + N + 1;         // [64]
  int* bar  = bsum + 64;           // [16] barrier counters
  int* rank = bar + 16;            // [E]
  int* csr  = rank + E;            // [E]
  size_t ioff = ((size_t)(N + N + 1 + 64 + 16 + 2 * E) * 4 + 15) & ~(size_t)15;
  unsigned short* A1  = (unsigned short*)((char*)d_ws + ioff);  // [N][256]
  unsigned short* h   = A1 + (size_t)N * 256;                   // [N][256]
  unsigned short* tb  = h + (size_t)N * 256;                    // [N][128]
  unsigned short* Wc1 = tb + (size_t)N * 128;                   // [256][256]
  unsigned short* Wc2 = Wc1 + 65536;                            // [256][256]

  int SB = (N + 1023) / 1024;  // 49 (<= 64 and <= 256 blocks)

  hipMemsetAsync(bar, 0, 16 * sizeof(int), stream);
  build_fused_kernel<<<256, 256, 0, stream>>>(x, W1l, W1r, W2l, W2r, Wc1, Wc2, A1,
                                              cnt, off, bsum, bar, rank, csr,
                                              src, dst, N, E, SB);

  gather1_kernel<<<(N + 3) / 4, 256, 0, stream>>>(A1 + 128, csr, off, A1, N);

  dim3 gg((N + 127) / 128, 2);
  gemm_bf16<0><<<gg, 256, 0, stream>>>(A1, Wc1, b1l, h, nullptr, N);
  gemm_bf16<1><<<gg, 256, 0, stream>>>(h, Wc2, b2l, tb, out, N);

  const int gblocks = (N + 3) / 4;  // 1 wave per node
  gather2_kernel<<<gblocks, 256, 0, stream>>>(tb, csr, off, out, N);
}